// Round 5
// baseline (222.444 us; speedup 1.0000x reference)
//
#include <hip/hip_runtime.h>
#include <stdint.h>

#define DEV __device__ __forceinline__

typedef unsigned short u16;
typedef u16   u16x8 __attribute__((ext_vector_type(8)));
typedef u16   u16x4 __attribute__((ext_vector_type(4)));
typedef u16   u16x2 __attribute__((ext_vector_type(2)));
typedef __bf16 bf16x8v __attribute__((ext_vector_type(8)));
typedef float f32x4 __attribute__((ext_vector_type(4)));

constexpr int NWIN = 81;          // 9x9 windows per batch
constexpr int BN   = 4 * NWIN;    // 324 total windows
constexpr float EPS = 1e-5f;
constexpr float SCALE = 0.07216878364870322f; // 192^-0.5

DEV u16 f2bf(float f) {            // fp32 -> bf16 RNE
    unsigned u = __builtin_bit_cast(unsigned, f);
    u += 0x7fffu + ((u >> 16) & 1u);
    return (u16)(u >> 16);
}

DEV f32x4 mfma16(bf16x8v a, bf16x8v b, f32x4 c) {
    return __builtin_amdgcn_mfma_f32_16x16x32_bf16(a, b, c, 0, 0, 0);
}

// ---------------- kernel 0: convert Wq|Wk|Wv fp32 -> bf16 (contiguous in ws)
__global__ void wconv(const float* __restrict__ wq, const float* __restrict__ wk,
                      const float* __restrict__ wv, u16* __restrict__ dst) {
    int idx = blockIdx.x * 256 + threadIdx.x;       // 3*36864 exact
    const float* src = (idx < 36864) ? wq : (idx < 73728 ? wk : wv);
    int r = (idx < 36864) ? idx : (idx < 73728 ? idx - 36864 : idx - 73728);
    dst[idx] = f2bf(src[r]);
}

// ---------------- kernel 1: per-pixel LN stats (mu, rsqrt(var+eps))
__global__ void ln_stats(const float* __restrict__ x, float* __restrict__ mu_g,
                         float* __restrict__ rs_g) {
    __shared__ float p1[8][132], p2[8][132];
    const int bh = blockIdx.x;               // 0..511
    const int b = bh >> 7, h = bh & 127;
    const int tid = threadIdx.x;
    const int w4 = tid & 31, cg = tid >> 5;  // 8 channel groups
    const float* base = x + (((long)(b * 192 + cg)) * 128 + h) * 128 + 4 * w4;
    float4 s1 = {0, 0, 0, 0}, s2 = {0, 0, 0, 0};
    #pragma unroll 4
    for (int c = 0; c < 192; c += 8) {       // channel = cg + c
        float4 v = *(const float4*)(base + (long)c * 16384);
        s1.x += v.x; s1.y += v.y; s1.z += v.z; s1.w += v.w;
        s2.x += v.x * v.x; s2.y += v.y * v.y; s2.z += v.z * v.z; s2.w += v.w * v.w;
    }
    *(float4*)&p1[cg][4 * w4] = s1;
    *(float4*)&p2[cg][4 * w4] = s2;
    __syncthreads();
    if (tid < 128) {
        float a = 0.f, q = 0.f;
        #pragma unroll
        for (int g = 0; g < 8; ++g) { a += p1[g][tid]; q += p2[g][tid]; }
        float mu = a * (1.0f / 192.0f);
        float var = q * (1.0f / 192.0f) - mu * mu;
        long pix = ((long)(b * 128) + h) * 128 + tid;
        mu_g[pix] = mu;
        rs_g[pix] = rsqrtf(var + EPS);
    }
}

// ---------------- kernel 2: LN-apply + dense QKV GEMM over all pixels
// block = 128 consecutive pixels of one batch. 256 threads (4 waves).
// outputs: qk_g[pix][384] (q | k, ch-contig), vT_g[b*192+o][16384] (pix-contig)
__launch_bounds__(256, 3)
__global__ void qkv_kernel(const float* __restrict__ x, const u16* __restrict__ wbf,
                           const float* __restrict__ gamma, const float* __restrict__ beta,
                           const float* __restrict__ mu_g, const float* __restrict__ rs_g,
                           u16* __restrict__ qk_g, u16* __restrict__ vT_g) {
    __shared__ u16 lx[128 * 200];           // [token][c]
    __shared__ float gb[384];

    const int tid = threadIdx.x;
    const int b = blockIdx.x >> 7, tile = blockIdx.x & 127;
    const int hw0 = tile * 128;

    if (tid < 192) { gb[tid] = gamma[tid]; gb[192 + tid] = beta[tid]; }
    __syncthreads();

    // ---- stage: read x (coalesced float4 along w), normalize, bf16 -> LDS
    {
        const int pxq = tid & 31, ch0 = tid >> 5;   // 32 pixel-quads x 8 ch-groups
        const float* xb = x + (((long)(b * 192 + ch0)) << 14) + hw0 + 4 * pxq;
        const float4 mu4 = *(const float4*)&mu_g[((long)b << 14) + hw0 + 4 * pxq];
        const float4 rs4 = *(const float4*)&rs_g[((long)b << 14) + hw0 + 4 * pxq];
        #pragma unroll 6
        for (int c = ch0; c < 192; c += 8) {
            float4 v = *(const float4*)(xb + ((long)(c - ch0) << 14));
            float g = gb[c], be = gb[192 + c];
            lx[(4 * pxq + 0) * 200 + c] = f2bf((v.x - mu4.x) * rs4.x * g + be);
            lx[(4 * pxq + 1) * 200 + c] = f2bf((v.y - mu4.y) * rs4.y * g + be);
            lx[(4 * pxq + 2) * 200 + c] = f2bf((v.z - mu4.z) * rs4.z * g + be);
            lx[(4 * pxq + 3) * 200 + c] = f2bf((v.w - mu4.w) * rs4.w * g + be);
        }
    }
    __syncthreads();

    const int wv_ = tid >> 6, lane = tid & 63;
    const int l15 = lane & 15, g4 = lane >> 4;
    const u16* wq_b = wbf;
    const u16* wk_b = wbf + 36864;
    const u16* wv_b = wbf + 73728;

    // Q, K : out[s][o] ; 8 s-tiles (waves own 2 each), 12 o-tiles
    for (int qk = 0; qk < 2; ++qk) {
        const u16* wsrc = qk ? wk_b : wq_b;
        const int obase = qk ? 192 : 0;
        for (int ntp = 0; ntp < 6; ++ntp) {
            f32x4 acc[2][2] = {};
            #pragma unroll
            for (int ks = 0; ks < 6; ++ks) {
                bf16x8v a0 = *(const bf16x8v*)&lx[(16 * (2 * wv_ + 0) + l15) * 200 + 32 * ks + 8 * g4];
                bf16x8v a1 = *(const bf16x8v*)&lx[(16 * (2 * wv_ + 1) + l15) * 200 + 32 * ks + 8 * g4];
                bf16x8v b0 = *(const bf16x8v*)&wsrc[(16 * (2 * ntp + 0) + l15) * 192 + 32 * ks + 8 * g4];
                bf16x8v b1 = *(const bf16x8v*)&wsrc[(16 * (2 * ntp + 1) + l15) * 192 + 32 * ks + 8 * g4];
                acc[0][0] = mfma16(a0, b0, acc[0][0]); acc[0][1] = mfma16(a0, b1, acc[0][1]);
                acc[1][0] = mfma16(a1, b0, acc[1][0]); acc[1][1] = mfma16(a1, b1, acc[1][1]);
            }
            #pragma unroll
            for (int mi = 0; mi < 2; ++mi)
                #pragma unroll
                for (int ni = 0; ni < 2; ++ni)
                    #pragma unroll
                    for (int r = 0; r < 4; ++r) {
                        int s = 16 * (2 * wv_ + mi) + 4 * g4 + r;
                        int o = 16 * (2 * ntp + ni) + l15;
                        qk_g[(((long)b << 14) + hw0 + s) * 384 + obase + o] = f2bf(acc[mi][ni][r]);
                    }
        }
    }
    // V^T : out[o][s] ; 12 o-tiles (waves own 3 each), 8 s-tiles
    for (int mtl = 0; mtl < 3; ++mtl) {
        int mt = 3 * wv_ + mtl;
        for (int ntp = 0; ntp < 4; ++ntp) {
            f32x4 acc[2] = {};
            #pragma unroll
            for (int ks = 0; ks < 6; ++ks) {
                bf16x8v a  = *(const bf16x8v*)&wv_b[(16 * mt + l15) * 192 + 32 * ks + 8 * g4];
                bf16x8v b0 = *(const bf16x8v*)&lx[(16 * (2 * ntp + 0) + l15) * 200 + 32 * ks + 8 * g4];
                bf16x8v b1 = *(const bf16x8v*)&lx[(16 * (2 * ntp + 1) + l15) * 200 + 32 * ks + 8 * g4];
                acc[0] = mfma16(a, b0, acc[0]); acc[1] = mfma16(a, b1, acc[1]);
            }
            #pragma unroll
            for (int ni = 0; ni < 2; ++ni)
                #pragma unroll
                for (int r = 0; r < 4; ++r) {
                    int o = 16 * mt + 4 * g4 + r;
                    int s = 16 * (2 * ntp + ni) + l15;
                    vT_g[(((long)(b * 192 + o)) << 14) + hw0 + s] = f2bf(acc[ni][r]);
                }
        }
    }
}

// ---------------- kernel 3: per (window, head) attention. 512 threads (8 waves).
// LDS: Q[256][40] + K[256][40] (P[256][72] overlays Q+K) + VT[32][264]
__launch_bounds__(512, 2)
__global__ void attn_kernel(const u16* __restrict__ qk_g, const u16* __restrict__ vT_g,
                            float* __restrict__ out_win) {
    __shared__ u16 smem[28928];
    u16* Qs = smem;            // [256][40]
    u16* Ks = smem + 10240;    // [256][40]
    u16* Ps = smem;            // overlay [256][72]
    u16* Vs = smem + 20480;    // [32][264]

    const int tid = threadIdx.x;
    const int win = blockIdx.x / 6, h = blockIdx.x % 6;
    const int b = win / NWIN, wi = win % NWIN;
    const int t0 = 14 * (wi / 9), l0 = 14 * (wi % 9);

    { // stage Q,K head-slices [256][32] and V^T slice [32][256]
        int s = tid >> 1, hf = tid & 1;
        int p = (t0 + (s >> 4)) * 128 + l0 + (s & 15);
        const u16* src = qk_g + (((long)b << 14) + p) * 384 + 32 * h + 16 * hf;
        *(u16x8*)&Qs[s * 40 + 16 * hf    ] = *(const u16x8*)(src);
        *(u16x8*)&Qs[s * 40 + 16 * hf + 8] = *(const u16x8*)(src + 8);
        *(u16x8*)&Ks[s * 40 + 16 * hf    ] = *(const u16x8*)(src + 192);
        *(u16x8*)&Ks[s * 40 + 16 * hf + 8] = *(const u16x8*)(src + 200);

        int r = tid >> 4, seg = tid & 15;
        const u16* vsrc = vT_g + (((long)(b * 192 + 32 * h + r)) << 14) + (t0 + seg) * 128 + l0;
        #pragma unroll
        for (int j = 0; j < 8; ++j)
            *(u16x2*)&Vs[r * 264 + 16 * seg + 2 * j] = *(const u16x2*)(vsrc + 2 * j);
    }
    __syncthreads();

    const int lane = tid & 63, wv_ = tid >> 6;
    const int l15 = lane & 15, g4 = lane >> 4;

    // scoresT[key][q] = K . Q^T ; wave owns q-tiles {2wv_, 2wv_+1}
    f32x4 sc[16][2];
    {
        bf16x8v bq0 = *(const bf16x8v*)&Qs[(16 * (2 * wv_ + 0) + l15) * 40 + 8 * g4];
        bf16x8v bq1 = *(const bf16x8v*)&Qs[(16 * (2 * wv_ + 1) + l15) * 40 + 8 * g4];
        const f32x4 z = {0.f, 0.f, 0.f, 0.f};
        #pragma unroll
        for (int mt = 0; mt < 16; ++mt) {
            bf16x8v a = *(const bf16x8v*)&Ks[(16 * mt + l15) * 40 + 8 * g4];
            sc[mt][0] = mfma16(a, bq0, z);
            sc[mt][1] = mfma16(a, bq1, z);
        }
    }

    // softmax over keys: lane-local 64 vals + xor16 + xor32
    float rden[2];
    #pragma unroll
    for (int nq = 0; nq < 2; ++nq) {
        float mx = -1e30f;
        #pragma unroll
        for (int mt = 0; mt < 16; ++mt)
            #pragma unroll
            for (int r = 0; r < 4; ++r) mx = fmaxf(mx, sc[mt][nq][r]);
        mx = fmaxf(mx, __shfl_xor(mx, 16, 64));
        mx = fmaxf(mx, __shfl_xor(mx, 32, 64));
        float sum = 0.f;
        #pragma unroll
        for (int mt = 0; mt < 16; ++mt)
            #pragma unroll
            for (int r = 0; r < 4; ++r) {
                float p = __expf((sc[mt][nq][r] - mx) * SCALE);
                sc[mt][nq][r] = p; sum += p;
            }
        sum += __shfl_xor(sum, 16, 64);
        sum += __shfl_xor(sum, 32, 64);
        rden[nq] = 1.0f / sum;
    }

    // PV: outT[dv][q] = V^T . P^T, P staged per 64-key chunk (Ps overlays Q/K)
    f32x4 oacc[2][2] = {};
    #pragma unroll
    for (int kc = 0; kc < 4; ++kc) {
        __syncthreads();   // prior readers of Ps region (or Q/K reads at kc=0) done
        #pragma unroll
        for (int mtl = 0; mtl < 4; ++mtl) {
            int mt = 4 * kc + mtl;
            #pragma unroll
            for (int nq = 0; nq < 2; ++nq) {
                int q = 16 * (2 * wv_ + nq) + l15;
                u16x4 pk = { f2bf(sc[mt][nq][0]), f2bf(sc[mt][nq][1]),
                             f2bf(sc[mt][nq][2]), f2bf(sc[mt][nq][3]) };
                *(u16x4*)&Ps[q * 72 + 16 * mtl + 4 * g4] = pk;
            }
        }
        __syncthreads();
        #pragma unroll
        for (int ksl = 0; ksl < 2; ++ksl) {
            bf16x8v a0 = *(const bf16x8v*)&Vs[(l15) * 264 + 64 * kc + 32 * ksl + 8 * g4];
            bf16x8v a1 = *(const bf16x8v*)&Vs[(16 + l15) * 264 + 64 * kc + 32 * ksl + 8 * g4];
            bf16x8v b0 = *(const bf16x8v*)&Ps[(16 * (2 * wv_ + 0) + l15) * 72 + 32 * ksl + 8 * g4];
            bf16x8v b1 = *(const bf16x8v*)&Ps[(16 * (2 * wv_ + 1) + l15) * 72 + 32 * ksl + 8 * g4];
            oacc[0][0] = mfma16(a0, b0, oacc[0][0]); oacc[0][1] = mfma16(a0, b1, oacc[0][1]);
            oacc[1][0] = mfma16(a1, b0, oacc[1][0]); oacc[1][1] = mfma16(a1, b1, oacc[1][1]);
        }
    }

    // epilogue: divide by denom, write out_win[win][c][s]
    #pragma unroll
    for (int mtv = 0; mtv < 2; ++mtv)
        #pragma unroll
        for (int nq = 0; nq < 2; ++nq)
            #pragma unroll
            for (int r = 0; r < 4; ++r) {
                int c = 32 * h + 16 * mtv + 4 * g4 + r;
                int q = 16 * (2 * wv_ + nq) + l15;
                out_win[((long)win * 192 + c) * 256 + q] = oacc[mtv][nq][r] * rden[nq];
            }
}

// ---------------- kernel 4: overlap-add gather + divide by COUNT
__global__ void gather_kernel(const float* __restrict__ out_win, float* __restrict__ out) {
    int idx = blockIdx.x * 256 + threadIdx.x;       // 12,582,912 exact
    int w = idx & 127, hh = (idx >> 7) & 127;
    int v = idx >> 14; int c = v % 192, b = v / 192;
    int khmin = (hh - 2) / 14; if (khmin < 0) khmin = 0;
    int khmax = hh / 14; if (khmax > 8) khmax = 8;
    int kwmin = (w - 2) / 14; if (kwmin < 0) kwmin = 0;
    int kwmax = w / 14; if (kwmax > 8) kwmax = 8;
    float acc = 0.f; int cnt = 0;
    for (int ih = khmin; ih <= khmax; ++ih)
        for (int iw = kwmin; iw <= kwmax; ++iw) {
            int win = b * NWIN + ih * 9 + iw;
            int s = (hh - 14 * ih) * 16 + (w - 14 * iw);
            acc += out_win[((long)win * 192 + c) * 256 + s];
            ++cnt;
        }
    float rc = (cnt == 1) ? 1.0f : (cnt == 2 ? 0.5f : 0.25f);  // cnt in {1,2,4}
    out[idx] = acc * rc;
}

extern "C" void kernel_launch(void* const* d_in, const int* in_sizes, int n_in,
                              void* d_out, int out_size, void* d_ws, size_t ws_size,
                              hipStream_t stream) {
    const float* x     = (const float*)d_in[0];
    const float* Wq    = (const float*)d_in[1];
    const float* Wk    = (const float*)d_in[2];
    const float* Wv    = (const float*)d_in[3];
    const float* gamma = (const float*)d_in[4];
    const float* beta  = (const float*)d_in[5];

    char* ws = (char*)d_ws;
    // layout: wbf 221184 | mu_g 262144 | rs_g 262144 | qk_g 50331648 | vT_g 25165824 | out_win 63700992
    u16*   wbf     = (u16*)ws;
    float* mu_g    = (float*)(ws + 221184);
    float* rs_g    = (float*)(ws + 483328);
    u16*   qk_g    = (u16*)(ws + 745472);
    u16*   vT_g    = (u16*)(ws + 51077120);
    float* out_win = (float*)(ws + 76242944);

    wconv<<<dim3(432), dim3(256), 0, stream>>>(Wq, Wk, Wv, wbf);
    ln_stats<<<dim3(512), dim3(256), 0, stream>>>(x, mu_g, rs_g);
    qkv_kernel<<<dim3(512), dim3(256), 0, stream>>>(x, wbf, gamma, beta, mu_g, rs_g, qk_g, vT_g);
    attn_kernel<<<dim3(BN * 6), dim3(512), 0, stream>>>(qk_g, vT_g, out_win);
    gather_kernel<<<dim3(49152), dim3(256), 0, stream>>>(out_win, (float*)d_out);
}